// Round 3
// baseline (115.444 us; speedup 1.0000x reference)
//
#include <hip/hip_runtime.h>
#include <math.h>

// B=32, S=1024, D=256, V=50000.
// loss(b,s) = log S(k) - 0.98*k - 0.1*dot - 344.3348757
//   k = ||preds[b,:,s]||, dot = <emb[target], preds[b,:,s]>
//   S = 1 + sum_{j>=1} prod_{i<j} (k^2/4)/((i+1)(128+i))   (0F1(;128;k^2/4))
// derived from logcmk with v=127: logIv = 127*log(k/2) - lgamma(128) + log S,
// constants folded: -127*ln2 - lgamma(128) + 128*ln(2pi) = -344.3348757.
// out = sum(loss*mask)/sum(mask), mask = target != 1.

constexpr int Dc = 256;
constexpr int Sc = 1024;
constexpr int Bc = 32;
constexpr int TILE = 16;                  // positions per block
constexpr int NBLK = Bc * Sc / TILE;      // 2048

using f4 = __attribute__((ext_vector_type(4))) float;

__global__ __launch_bounds__(256) void nllvmf_fused(
    const float* __restrict__ preds,
    const float* __restrict__ emb,
    const int*   __restrict__ target,
    float*       __restrict__ out,
    float*       __restrict__ acc)   // acc[0]=loss, acc[1]=mask, ((int*)acc)[2]=done
{
    __shared__ float s_r[4][2][16];       // [wave][n2|dot][pos]

    const int tid = threadIdx.x;
    const int blk = blockIdx.x;
    const int b   = blk >> 6;             // 64 blocks per batch row
    const int s0  = (blk & 63) * TILE;
    const int w   = tid >> 6;             // wave: dim slice w*64..+63
    const int l   = tid & 63;
    const int td  = l >> 2;               // 16 d-chunks of 4 dims
    const int sg  = l & 3;                // 4 position-groups of 4
    const int d0  = w * 64 + td * 4;
    const int p0  = s0 + sg * 4;

    // targets for this thread's 4 positions (one int4)
    const int4 tg4 = *reinterpret_cast<const int4*>(target + b * Sc + p0);
    const int tg[4] = {tg4.x, tg4.y, tg4.z, tg4.w};

    // 4 emb gathers (independent) + 4 coalesced non-temporal preds loads
    float e[4][4];
    #pragma unroll
    for (int j = 0; j < 4; ++j) {
        f4 v = *reinterpret_cast<const f4*>(emb + (size_t)tg[j] * Dc + d0);
        e[j][0] = v.x; e[j][1] = v.y; e[j][2] = v.z; e[j][3] = v.w;
    }
    const float* pb = preds + (size_t)b * Dc * Sc + (size_t)d0 * Sc + p0;
    float pq[4][4];
    #pragma unroll
    for (int q = 0; q < 4; ++q) {
        f4 p = __builtin_nontemporal_load(reinterpret_cast<const f4*>(pb + (size_t)q * Sc));
        pq[q][0] = p.x; pq[q][1] = p.y; pq[q][2] = p.z; pq[q][3] = p.w;
    }

    float n2[4] = {0.f,0.f,0.f,0.f};
    float dt[4] = {0.f,0.f,0.f,0.f};
    #pragma unroll
    for (int q = 0; q < 4; ++q)
        #pragma unroll
        for (int j = 0; j < 4; ++j) {
            n2[j] = fmaf(pq[q][j], pq[q][j], n2[j]);
            dt[j] = fmaf(pq[q][j], e[j][q], dt[j]);
        }

    // reduce over td (lane bits 2..5)
    #pragma unroll
    for (int m = 4; m <= 32; m <<= 1)
        #pragma unroll
        for (int j = 0; j < 4; ++j) {
            n2[j] += __shfl_xor(n2[j], m, 64);
            dt[j] += __shfl_xor(dt[j], m, 64);
        }

    if (td == 0) {
        #pragma unroll
        for (int j = 0; j < 4; ++j) {
            s_r[w][0][sg * 4 + j] = n2[j];
            s_r[w][1][sg * 4 + j] = dt[j];
        }
    }
    __syncthreads();

    if (tid < 16) {
        const float norm2 = s_r[0][0][tid] + s_r[1][0][tid] + s_r[2][0][tid] + s_r[3][0][tid];
        const float dot   = s_r[0][1][tid] + s_r[1][1][tid] + s_r[2][1][tid] + s_r[3][1][tid];
        const int   tgt   = target[b * Sc + s0 + tid];

        const float k = sqrtf(norm2);
        const float r = 0.25f * norm2;

        // S = 0F1(;128;r), 32-term recurrence; reciprocals are literals
        constexpr float INV[32] = {
            1.0f/128.0f,  1.0f/258.0f,  1.0f/390.0f,  1.0f/524.0f,
            1.0f/660.0f,  1.0f/798.0f,  1.0f/938.0f,  1.0f/1080.0f,
            1.0f/1224.0f, 1.0f/1370.0f, 1.0f/1518.0f, 1.0f/1668.0f,
            1.0f/1820.0f, 1.0f/1974.0f, 1.0f/2130.0f, 1.0f/2288.0f,
            1.0f/2448.0f, 1.0f/2610.0f, 1.0f/2774.0f, 1.0f/2940.0f,
            1.0f/3108.0f, 1.0f/3278.0f, 1.0f/3450.0f, 1.0f/3624.0f,
            1.0f/3800.0f, 1.0f/3978.0f, 1.0f/4158.0f, 1.0f/4340.0f,
            1.0f/4524.0f, 1.0f/4710.0f, 1.0f/4898.0f, 1.0f/5088.0f };
        float t = 1.0f, S = 1.0f;
        #pragma unroll
        for (int j = 0; j < 32; ++j) { t *= r * INV[j]; S += t; }

        float loss = __logf(S) - 0.98f * k - 0.1f * dot - 344.3348757f;
        float msk  = (tgt != 1) ? 1.0f : 0.0f;
        loss *= msk;

        #pragma unroll
        for (int off = 8; off; off >>= 1) {
            loss += __shfl_down(loss, off, 16);
            msk  += __shfl_down(msk,  off, 16);
        }
        if (tid == 0) {
            atomicAdd(&acc[0], loss);
            atomicAdd(&acc[1], msk);
            __threadfence();
            const int done = atomicAdd((int*)acc + 2, 1);
            if (done == NBLK - 1) {
                __threadfence();
                const float ls = atomicAdd(&acc[0], 0.0f);
                const float ms = atomicAdd(&acc[1], 0.0f);
                out[0] = ls / ms;
            }
        }
    }
}

extern "C" void kernel_launch(void* const* d_in, const int* in_sizes, int n_in,
                              void* d_out, int out_size, void* d_ws, size_t ws_size,
                              hipStream_t stream) {
    const float* preds  = (const float*)d_in[0];
    const float* emb    = (const float*)d_in[1];
    const int*   target = (const int*)d_in[2];
    float* out = (float*)d_out;
    float* ws  = (float*)d_ws;

    hipMemsetAsync(ws, 0, 3 * sizeof(float), stream);
    nllvmf_fused<<<NBLK, 256, 0, stream>>>(preds, emb, target, out, ws);
}

// Round 4
// 19.259 us; speedup vs baseline: 5.9942x; 5.9942x over previous
//
#include <hip/hip_runtime.h>
#include <math.h>

// B=32, S=1024, D=256, V=50000.
// loss(b,s) = log S(k) - 0.98*k - 0.1*dot - 344.3348757
//   k = ||preds[b,:,s]||, dot = <emb[target], preds[b,:,s]>
//   S = 0F1(;128;k^2/4) = 1 + sum_{j>=1} prod_{i<j} (k^2/4)/((i+1)(128+i))
// (exact rewrite of -logcmk(256,k) - 0.1 dot + 0.02 k; verified absmax 0.0)
// out = sum(loss*mask)/sum(mask), mask = target != 1.

constexpr int Dc = 256;
constexpr int Sc = 1024;
constexpr int Bc = 32;
constexpr int TILE = 32;                  // positions per block
constexpr int NBLK = Bc * Sc / TILE;      // 1024

using f4 = __attribute__((ext_vector_type(4))) float;

__global__ __launch_bounds__(256) void nllvmf_main(
    const float* __restrict__ preds,
    const float* __restrict__ emb,
    const int*   __restrict__ target,
    float*       __restrict__ partial)    // [0..NBLK): loss, [NBLK..2N): mask
{
    __shared__ float s_r[4][2][32];       // [wave][n2|dot][pos]

    const int tid = threadIdx.x;
    const int blk = blockIdx.x;
    const int b   = blk >> 5;             // Sc/TILE = 32 blocks per batch row
    const int s0  = (blk & 31) * TILE;
    const int w   = tid >> 6;             // wave: dim slice w*64..+63
    const int l   = tid & 63;
    const int td  = l >> 2;               // 16 d-chunks of 4 dims
    const int sg  = l & 3;                // 4 position-groups of 4
    const int d0  = w * 64 + td * 4;
    const int p0  = s0 + sg * 4;          // tile A; tile B = p0 + 16

    // targets for this thread's 8 positions (two int4 loads)
    const int4 tA = *reinterpret_cast<const int4*>(target + b * Sc + p0);
    const int4 tB = *reinterpret_cast<const int4*>(target + b * Sc + p0 + 16);
    const int tgA[4] = {tA.x, tA.y, tA.z, tA.w};
    const int tgB[4] = {tB.x, tB.y, tB.z, tB.w};

    // 8 coalesced preds float4 loads (issued up front, all independent)
    const float* pb = preds + (size_t)b * Dc * Sc + (size_t)d0 * Sc + p0;
    f4 pA[4], pB[4];
    #pragma unroll
    for (int q = 0; q < 4; ++q) {
        pA[q] = *reinterpret_cast<const f4*>(pb + (size_t)q * Sc);
        pB[q] = *reinterpret_cast<const f4*>(pb + (size_t)q * Sc + 16);
    }
    // 8 emb gathers (independent once targets arrive)
    f4 eA[4], eB[4];
    #pragma unroll
    for (int j = 0; j < 4; ++j) {
        eA[j] = *reinterpret_cast<const f4*>(emb + (size_t)tgA[j] * Dc + d0);
        eB[j] = *reinterpret_cast<const f4*>(emb + (size_t)tgB[j] * Dc + d0);
    }

    float n2A[4] = {0,0,0,0}, dtA[4] = {0,0,0,0};
    float n2B[4] = {0,0,0,0}, dtB[4] = {0,0,0,0};
    #pragma unroll
    for (int q = 0; q < 4; ++q)
        #pragma unroll
        for (int j = 0; j < 4; ++j) {
            n2A[j] = fmaf(pA[q][j], pA[q][j], n2A[j]);
            dtA[j] = fmaf(pA[q][j], eA[j][q], dtA[j]);
            n2B[j] = fmaf(pB[q][j], pB[q][j], n2B[j]);
            dtB[j] = fmaf(pB[q][j], eB[j][q], dtB[j]);
        }

    // reduce over td (lane bits 2..5)
    #pragma unroll
    for (int m = 4; m <= 32; m <<= 1)
        #pragma unroll
        for (int j = 0; j < 4; ++j) {
            n2A[j] += __shfl_xor(n2A[j], m, 64);
            dtA[j] += __shfl_xor(dtA[j], m, 64);
            n2B[j] += __shfl_xor(n2B[j], m, 64);
            dtB[j] += __shfl_xor(dtB[j], m, 64);
        }

    if (td == 0) {
        #pragma unroll
        for (int j = 0; j < 4; ++j) {
            s_r[w][0][sg * 4 + j]      = n2A[j];
            s_r[w][1][sg * 4 + j]      = dtA[j];
            s_r[w][0][16 + sg * 4 + j] = n2B[j];
            s_r[w][1][16 + sg * 4 + j] = dtB[j];
        }
    }
    __syncthreads();

    if (tid < 32) {
        const float norm2 = s_r[0][0][tid] + s_r[1][0][tid] + s_r[2][0][tid] + s_r[3][0][tid];
        const float dot   = s_r[0][1][tid] + s_r[1][1][tid] + s_r[2][1][tid] + s_r[3][1][tid];
        const int   tgt   = target[b * Sc + s0 + tid];

        const float k = sqrtf(norm2);
        const float r = 0.25f * norm2;

        // S = 0F1(;128;r), 32-term recurrence; reciprocals are literals
        constexpr float INV[32] = {
            1.0f/128.0f,  1.0f/258.0f,  1.0f/390.0f,  1.0f/524.0f,
            1.0f/660.0f,  1.0f/798.0f,  1.0f/938.0f,  1.0f/1080.0f,
            1.0f/1224.0f, 1.0f/1370.0f, 1.0f/1518.0f, 1.0f/1668.0f,
            1.0f/1820.0f, 1.0f/1974.0f, 1.0f/2130.0f, 1.0f/2288.0f,
            1.0f/2448.0f, 1.0f/2610.0f, 1.0f/2774.0f, 1.0f/2940.0f,
            1.0f/3108.0f, 1.0f/3278.0f, 1.0f/3450.0f, 1.0f/3624.0f,
            1.0f/3800.0f, 1.0f/3978.0f, 1.0f/4158.0f, 1.0f/4340.0f,
            1.0f/4524.0f, 1.0f/4710.0f, 1.0f/4898.0f, 1.0f/5088.0f };
        float t = 1.0f, S = 1.0f;
        #pragma unroll
        for (int j = 0; j < 32; ++j) { t *= r * INV[j]; S += t; }

        float loss = __logf(S) - 0.98f * k - 0.1f * dot - 344.3348757f;
        float msk  = (tgt != 1) ? 1.0f : 0.0f;
        loss *= msk;

        // lanes 0..31 active: xor partners stay in range
        #pragma unroll
        for (int m = 16; m; m >>= 1) {
            loss += __shfl_xor(loss, m, 64);
            msk  += __shfl_xor(msk,  m, 64);
        }
        if (tid == 0) {
            partial[blk]        = loss;
            partial[NBLK + blk] = msk;
        }
    }
}

__global__ __launch_bounds__(256) void nllvmf_finalize(
    const float* __restrict__ partial, float* __restrict__ out)
{
    __shared__ float sl[4], sm[4];
    const int tid = threadIdx.x;
    float l = 0.f, m = 0.f;
    for (int i = tid; i < NBLK; i += 256) {
        l += partial[i];
        m += partial[NBLK + i];
    }
    #pragma unroll
    for (int off = 32; off; off >>= 1) {
        l += __shfl_down(l, off, 64);
        m += __shfl_down(m, off, 64);
    }
    if ((tid & 63) == 0) { sl[tid >> 6] = l; sm[tid >> 6] = m; }
    __syncthreads();
    if (tid == 0)
        out[0] = (sl[0] + sl[1] + sl[2] + sl[3]) / (sm[0] + sm[1] + sm[2] + sm[3]);
}

extern "C" void kernel_launch(void* const* d_in, const int* in_sizes, int n_in,
                              void* d_out, int out_size, void* d_ws, size_t ws_size,
                              hipStream_t stream) {
    const float* preds  = (const float*)d_in[0];
    const float* emb    = (const float*)d_in[1];
    const int*   target = (const int*)d_in[2];
    float* out = (float*)d_out;
    float* ws  = (float*)d_ws;

    nllvmf_main<<<NBLK, 256, 0, stream>>>(preds, emb, target, ws);
    nllvmf_finalize<<<1, 256, 0, stream>>>(ws, out);
}

// Round 5
// 18.732 us; speedup vs baseline: 6.1630x; 1.0282x over previous
//
#include <hip/hip_runtime.h>
#include <math.h>

// B=32, S=1024, D=256, V=50000.
// loss(b,s) = log S(k) - 0.98*k - 0.1*dot - 344.3348757
//   k = ||preds[b,:,s]||, dot = <emb[target], preds[b,:,s]>
//   S = 0F1(;128;k^2/4) = 1 + sum_{j>=1} prod_{i<j} (k^2/4)/((i+1)(128+i))
// (exact rewrite of -logcmk(256,k) - 0.1 dot + 0.02 k; verified absmax 0.0)
// out = sum(loss*mask)/sum(mask), mask = target != 1.

constexpr int Dc = 256;
constexpr int Sc = 1024;
constexpr int Bc = 32;
constexpr int TILE = 64;                  // positions per block
constexpr int NBLK = Bc * Sc / TILE;      // 512
constexpr int NW   = 8;                   // waves per block (512 threads)

using f4 = __attribute__((ext_vector_type(4))) float;

__global__ __launch_bounds__(512) void nllvmf_main(
    const float* __restrict__ preds,
    const float* __restrict__ emb,
    const int*   __restrict__ target,
    float*       __restrict__ partial)    // [0..NBLK): loss, [NBLK..2N): mask
{
    __shared__ float s_r[NW][2][64];      // [wave][n2|dot][pos]

    const int tid = threadIdx.x;
    const int blk = blockIdx.x;
    const int b   = blk >> 4;             // Sc/TILE = 16 blocks per batch row
    const int s0  = (blk & 15) * TILE;
    const int w   = tid >> 6;             // wave: dim slice w*32 .. w*32+31
    const int l   = tid & 63;
    const int td  = l >> 3;               // 8 dim-groups of 4 dims
    const int sg  = l & 7;                // 8 position-groups of 8
    const int d0  = w * 32 + td * 4;
    const int p0  = s0 + sg * 8;

    // targets for this thread's 8 positions (two int4, 256B dense per wave)
    const int4 tA = *reinterpret_cast<const int4*>(target + b * Sc + p0);
    const int4 tB = *reinterpret_cast<const int4*>(target + b * Sc + p0 + 4);
    const int tg[8] = {tA.x, tA.y, tA.z, tA.w, tB.x, tB.y, tB.z, tB.w};

    // 8 coalesced preds float4 (dims d0..d0+3 x position-chunks c=0,1)
    const float* pb = preds + (size_t)b * Dc * Sc + (size_t)d0 * Sc + p0;
    f4 p[4][2];
    #pragma unroll
    for (int q = 0; q < 4; ++q) {
        p[q][0] = *reinterpret_cast<const f4*>(pb + (size_t)q * Sc);
        p[q][1] = *reinterpret_cast<const f4*>(pb + (size_t)q * Sc + 4);
    }
    // 8 emb gathers: one float4 (dims d0..d0+3) per target row;
    // per instruction: 8 rows x 128B-dense td-lanes
    f4 e[8];
    #pragma unroll
    for (int j = 0; j < 8; ++j)
        e[j] = *reinterpret_cast<const f4*>(emb + (size_t)tg[j] * Dc + d0);

    float n2[8] = {0,0,0,0,0,0,0,0};
    float dt[8] = {0,0,0,0,0,0,0,0};
    #pragma unroll
    for (int q = 0; q < 4; ++q)
        #pragma unroll
        for (int j = 0; j < 8; ++j) {
            const float pv = p[q][j >> 2][j & 3];
            n2[j] = fmaf(pv, pv, n2[j]);
            dt[j] = fmaf(pv, e[j][q], dt[j]);
        }

    // butterfly over td (lane bits 3..5): sum this wave's 32 dims
    #pragma unroll
    for (int m = 8; m <= 32; m <<= 1)
        #pragma unroll
        for (int j = 0; j < 8; ++j) {
            n2[j] += __shfl_xor(n2[j], m, 64);
            dt[j] += __shfl_xor(dt[j], m, 64);
        }

    if (td == 0) {
        #pragma unroll
        for (int j = 0; j < 8; ++j) {
            s_r[w][0][sg * 8 + j] = n2[j];
            s_r[w][1][sg * 8 + j] = dt[j];
        }
    }
    __syncthreads();

    if (tid < 64) {
        float norm2 = 0.f, dot = 0.f;
        #pragma unroll
        for (int w2 = 0; w2 < NW; ++w2) {
            norm2 += s_r[w2][0][tid];
            dot   += s_r[w2][1][tid];
        }
        const int tgt = target[b * Sc + s0 + tid];

        const float k = sqrtf(norm2);
        const float r = 0.25f * norm2;

        // S = 0F1(;128;r), 32-term recurrence; reciprocals are literals
        constexpr float INV[32] = {
            1.0f/128.0f,  1.0f/258.0f,  1.0f/390.0f,  1.0f/524.0f,
            1.0f/660.0f,  1.0f/798.0f,  1.0f/938.0f,  1.0f/1080.0f,
            1.0f/1224.0f, 1.0f/1370.0f, 1.0f/1518.0f, 1.0f/1668.0f,
            1.0f/1820.0f, 1.0f/1974.0f, 1.0f/2130.0f, 1.0f/2288.0f,
            1.0f/2448.0f, 1.0f/2610.0f, 1.0f/2774.0f, 1.0f/2940.0f,
            1.0f/3108.0f, 1.0f/3278.0f, 1.0f/3450.0f, 1.0f/3624.0f,
            1.0f/3800.0f, 1.0f/3978.0f, 1.0f/4158.0f, 1.0f/4340.0f,
            1.0f/4524.0f, 1.0f/4710.0f, 1.0f/4898.0f, 1.0f/5088.0f };
        float t = 1.0f, S = 1.0f;
        #pragma unroll
        for (int j = 0; j < 32; ++j) { t *= r * INV[j]; S += t; }

        float loss = __logf(S) - 0.98f * k - 0.1f * dot - 344.3348757f;
        float msk  = (tgt != 1) ? 1.0f : 0.0f;
        loss *= msk;

        #pragma unroll
        for (int m = 32; m; m >>= 1) {
            loss += __shfl_xor(loss, m, 64);
            msk  += __shfl_xor(msk,  m, 64);
        }
        if (tid == 0) {
            partial[blk]        = loss;
            partial[NBLK + blk] = msk;
        }
    }
}

__global__ __launch_bounds__(256) void nllvmf_finalize(
    const float* __restrict__ partial, float* __restrict__ out)
{
    __shared__ float sl[4], sm[4];
    const int tid = threadIdx.x;
    float l = 0.f, m = 0.f;
    for (int i = tid; i < NBLK; i += 256) {
        l += partial[i];
        m += partial[NBLK + i];
    }
    #pragma unroll
    for (int off = 32; off; off >>= 1) {
        l += __shfl_down(l, off, 64);
        m += __shfl_down(m, off, 64);
    }
    if ((tid & 63) == 0) { sl[tid >> 6] = l; sm[tid >> 6] = m; }
    __syncthreads();
    if (tid == 0)
        out[0] = (sl[0] + sl[1] + sl[2] + sl[3]) / (sm[0] + sm[1] + sm[2] + sm[3]);
}

extern "C" void kernel_launch(void* const* d_in, const int* in_sizes, int n_in,
                              void* d_out, int out_size, void* d_ws, size_t ws_size,
                              hipStream_t stream) {
    const float* preds  = (const float*)d_in[0];
    const float* emb    = (const float*)d_in[1];
    const int*   target = (const int*)d_in[2];
    float* out = (float*)d_out;
    float* ws  = (float*)d_ws;

    nllvmf_main<<<NBLK, 512, 0, stream>>>(preds, emb, target, ws);
    nllvmf_finalize<<<1, 256, 0, stream>>>(ws, out);
}